// Round 1
// baseline (699.852 us; speedup 1.0000x reference)
//
#include <hip/hip_runtime.h>

typedef unsigned short u16;
typedef __attribute__((ext_vector_type(4))) float f32x4;
typedef __attribute__((ext_vector_type(8))) short bf16x8;
typedef __attribute__((ext_vector_type(4))) unsigned short us4;

#define B_ 4
#define S_ 2048
#define D_ 1024
#define H_ 8
#define DH_ 128
#define MROWS (B_ * S_)   // 8192
#define LOG2E 1.4426950408889634f

__device__ __forceinline__ u16 f2bf(float f) {
  unsigned u = __float_as_uint(f);
  u += 0x7fffu + ((u >> 16) & 1u);   // round-to-nearest-even
  return (u16)(u >> 16);
}

__device__ __forceinline__ void gload_lds16(const void* g, void* l) {
  __builtin_amdgcn_global_load_lds(
      (const __attribute__((address_space(1))) void*)g,
      (__attribute__((address_space(3))) void*)l, 16, 0, 0);
}

// ---------------- cast f32 -> bf16, vectorized x4 ----------------
__global__ void cast_bf16(const float* __restrict__ src, u16* __restrict__ dst, int n4) {
  int i = blockIdx.x * blockDim.x + threadIdx.x;
  int st = gridDim.x * blockDim.x;
  for (; i < n4; i += st) {
    float4 v = reinterpret_cast<const float4*>(src)[i];
    us4 o = { f2bf(v.x), f2bf(v.y), f2bf(v.z), f2bf(v.w) };
    reinterpret_cast<us4*>(dst)[i] = o;
  }
}

// ---------------- fused QKV projection GEMM ----------------
// C[row][col] = sum_k A[row][k] * W[col][k]   (y = x @ W^T, both contiguous in k)
// z=0: A=qb,W=Wq -> Qo row-major; z=1: A=kb,W=Wk -> Ko row-major;
// z=2: A=kb,W=Wv -> Vt transposed per-batch: Vt[(b*1024+col)*2048 + s]
#define BM 128
#define BN 128
#define BKK 32

__global__ __launch_bounds__(256) void gemm_qkv(
    const u16* __restrict__ qb, const u16* __restrict__ kb,
    const u16* __restrict__ wq, const u16* __restrict__ wk, const u16* __restrict__ wv,
    u16* __restrict__ Qo, u16* __restrict__ Ko, u16* __restrict__ Vt)
{
  const int z = blockIdx.z;
  const u16* A = (z == 0) ? qb : kb;
  const u16* W = (z == 0) ? wq : (z == 1) ? wk : wv;
  constexpr int K = D_;

  __shared__ __align__(16) u16 sA[2][BM * BKK];
  __shared__ __align__(16) u16 sB[2][BN * BKK];

  const int tid = threadIdx.x;
  const int w = tid >> 6, lane = tid & 63;
  const int brow = blockIdx.y * BM, bcol = blockIdx.x * BN;

  // staging: each wave stages 2x16 rows of A and of B per K-step; lane l covers
  // row (l>>2), 16B chunk (l&3) -> LDS linear (wave-uniform base + lane*16)
  const int srow = w * 32 + (lane >> 2);
  const int scol = (lane & 3) * 8;
  const u16* gA = A + (brow + srow) * K + scol;
  const u16* gW = W + (bcol + srow) * K + scol;

  const int wr = (w >> 1) * 64, wc = (w & 1) * 64;
  const int fr = lane & 15, fg = lane >> 4;

  f32x4 acc[4][4] = {};

#define STAGE(bufi, k0) do { \
    gload_lds16(gA + (k0),          &sA[bufi][(w * 32) * BKK]);      \
    gload_lds16(gA + 16 * K + (k0), &sA[bufi][(w * 32 + 16) * BKK]); \
    gload_lds16(gW + (k0),          &sB[bufi][(w * 32) * BKK]);      \
    gload_lds16(gW + 16 * K + (k0), &sB[bufi][(w * 32 + 16) * BKK]); \
  } while (0)

  STAGE(0, 0);
  int cur = 0;
  for (int t = 0; t < K / BKK; ++t) {
    __syncthreads();   // drains vmcnt (stage done) + lgkm (prev reads done)
    if (t + 1 < K / BKK) STAGE(cur ^ 1, (t + 1) * BKK);
    bf16x8 af[4], bfr[4];
#pragma unroll
    for (int m = 0; m < 4; ++m)
      af[m] = *reinterpret_cast<const bf16x8*>(&sA[cur][(wr + m * 16 + fr) * BKK + fg * 8]);
#pragma unroll
    for (int n = 0; n < 4; ++n)
      bfr[n] = *reinterpret_cast<const bf16x8*>(&sB[cur][(wc + n * 16 + fr) * BKK + fg * 8]);
#pragma unroll
    for (int m = 0; m < 4; ++m)
#pragma unroll
      for (int n = 0; n < 4; ++n)
        acc[m][n] = __builtin_amdgcn_mfma_f32_16x16x32_bf16(af[m], bfr[n], acc[m][n], 0, 0, 0);
    cur ^= 1;
  }
#undef STAGE

  if (z < 2) {
    u16* Cp = (z == 0) ? Qo : Ko;
#pragma unroll
    for (int m = 0; m < 4; ++m)
#pragma unroll
      for (int n = 0; n < 4; ++n) {
        int row = brow + wr + m * 16 + fg * 4;
        int col = bcol + wc + n * 16 + fr;
#pragma unroll
        for (int r = 0; r < 4; ++r)
          Cp[(row + r) * D_ + col] = f2bf(acc[m][n][r]);
      }
  } else {
    // transposed store: rows r=0..3 are consecutive s -> pack 4 bf16 (8B store)
#pragma unroll
    for (int m = 0; m < 4; ++m) {
      int grow0 = brow + wr + m * 16 + fg * 4;
      int b = grow0 >> 11, s0 = grow0 & (S_ - 1);
#pragma unroll
      for (int n = 0; n < 4; ++n) {
        int col = bcol + wc + n * 16 + fr;
        us4 v = { f2bf(acc[m][n][0]), f2bf(acc[m][n][1]),
                  f2bf(acc[m][n][2]), f2bf(acc[m][n][3]) };
        *reinterpret_cast<us4*>(&Vt[((b << 10) + col) * S_ + s0]) = v;
      }
    }
  }
}

// ---------------- flash attention + residual ----------------
// block: 4 waves, each wave owns 16 q-rows; grid (S/64, H*B)
// QK^T: mfma(Q_frag, K_frag) -> S[q][key]; online softmax; P transposed via
// per-wave padded LDS bounce; PV: mfma(P_frag, Vt_frag) accumulates O[q][dh].
__global__ __launch_bounds__(256) void attn_fwd(
    const u16* __restrict__ Qb, const u16* __restrict__ Kb, const u16* __restrict__ Vt,
    const float* __restrict__ query, float* __restrict__ out)
{
  __shared__ __align__(16) u16 plds[4][16 * 40];   // stride 40 -> 2-way bank alias (free)
  const int tid = threadIdx.x;
  const int w = tid >> 6, lane = tid & 63;
  const int fr = lane & 15, fg = lane >> 4;
  const int hb = blockIdx.y;
  const int b = hb & (B_ - 1), h = hb >> 2;
  const int q0 = blockIdx.x * 64 + w * 16;

  bf16x8 qf[4];
  {
    const u16* Qp = Qb + (b * S_ + q0 + fr) * D_ + h * DH_ + fg * 8;
#pragma unroll
    for (int kk = 0; kk < 4; ++kk)
      qf[kk] = *reinterpret_cast<const bf16x8*>(Qp + kk * 32);
  }
  const u16* Kp = Kb + (b * S_ + fr) * D_ + h * DH_ + fg * 8;
  const u16* Vp = Vt + (((b << 10) + h * DH_ + fr) * S_) + fg * 8;

  const float NEG_INF = -__builtin_inff();
  float m_r[4] = { NEG_INF, NEG_INF, NEG_INF, NEG_INF };
  float l_r[4] = { 0.f, 0.f, 0.f, 0.f };
  f32x4 acc[8] = {};
  u16* myp = &plds[w][0];

  for (int kv = 0; kv < S_; kv += 32) {
    f32x4 s0 = {0.f, 0.f, 0.f, 0.f}, s1 = {0.f, 0.f, 0.f, 0.f};
#pragma unroll
    for (int kk = 0; kk < 4; ++kk) {
      bf16x8 k0 = *reinterpret_cast<const bf16x8*>(Kp + kv * D_ + kk * 32);
      bf16x8 k1 = *reinterpret_cast<const bf16x8*>(Kp + (kv + 16) * D_ + kk * 32);
      s0 = __builtin_amdgcn_mfma_f32_16x16x32_bf16(qf[kk], k0, s0, 0, 0, 0);
      s1 = __builtin_amdgcn_mfma_f32_16x16x32_bf16(qf[kk], k1, s1, 0, 0, 0);
    }
    float rmax[4], al[4], ps0[4], ps1[4], rs[4];
#pragma unroll
    for (int r = 0; r < 4; ++r) {
      s0[r] *= 0.03125f; s1[r] *= 0.03125f;   // 1/sqrt(D) = 1/32
      rmax[r] = fmaxf(s0[r], s1[r]);
    }
#pragma unroll
    for (int off = 1; off < 16; off <<= 1)
#pragma unroll
      for (int r = 0; r < 4; ++r)
        rmax[r] = fmaxf(rmax[r], __shfl_xor(rmax[r], off, 64));
#pragma unroll
    for (int r = 0; r < 4; ++r) {
      float mn = fmaxf(m_r[r], rmax[r]);
      al[r] = exp2f((m_r[r] - mn) * LOG2E);
      m_r[r] = mn;
      ps0[r] = exp2f((s0[r] - mn) * LOG2E);
      ps1[r] = exp2f((s1[r] - mn) * LOG2E);
      rs[r] = ps0[r] + ps1[r];
    }
#pragma unroll
    for (int off = 1; off < 16; off <<= 1)
#pragma unroll
      for (int r = 0; r < 4; ++r)
        rs[r] += __shfl_xor(rs[r], off, 64);
#pragma unroll
    for (int r = 0; r < 4; ++r)
      l_r[r] = l_r[r] * al[r] + rs[r];
#pragma unroll
    for (int n = 0; n < 8; ++n)
#pragma unroll
      for (int r = 0; r < 4; ++r)
        acc[n][r] *= al[r];

    // P (held as D-layout: row fg*4+r, col fr) -> LDS -> A-fragment layout
#pragma unroll
    for (int r = 0; r < 4; ++r) {
      myp[(fg * 4 + r) * 40 + fr]      = f2bf(ps0[r]);
      myp[(fg * 4 + r) * 40 + 16 + fr] = f2bf(ps1[r]);
    }
    asm volatile("s_waitcnt lgkmcnt(0)" ::: "memory");   // writes visible (wave-local)
    bf16x8 pa = *reinterpret_cast<const bf16x8*>(&myp[fr * 40 + fg * 8]);
    asm volatile("s_waitcnt lgkmcnt(0)" ::: "memory");   // read done before next overwrite
#pragma unroll
    for (int n = 0; n < 8; ++n) {
      bf16x8 vf = *reinterpret_cast<const bf16x8*>(Vp + (n * 16) * S_ + kv);
      acc[n] = __builtin_amdgcn_mfma_f32_16x16x32_bf16(pa, vf, acc[n], 0, 0, 0);
    }
  }

  float inv[4];
#pragma unroll
  for (int r = 0; r < 4; ++r) inv[r] = 1.0f / l_r[r];
#pragma unroll
  for (int n = 0; n < 8; ++n)
#pragma unroll
    for (int r = 0; r < 4; ++r) {
      int row = b * S_ + q0 + fg * 4 + r;
      int col = h * DH_ + n * 16 + fr;
      int idx = row * D_ + col;
      out[idx] = acc[n][r] * inv[r] + query[idx];   // + residual
    }
}

// ---------------- batch-norm (training-style, batch stats) ----------------
__global__ void bn_partial(const float* __restrict__ x, float* __restrict__ psum,
                           float* __restrict__ psum2) {
  int c = blockIdx.x * 256 + threadIdx.x;
  int r0 = blockIdx.y * 256;
  float s = 0.f, s2 = 0.f;
  for (int r = r0; r < r0 + 256; ++r) {
    float v = x[r * D_ + c];
    s += v; s2 += v * v;
  }
  psum[blockIdx.y * D_ + c] = s;
  psum2[blockIdx.y * D_ + c] = s2;
}

__global__ void bn_finalize(const float* __restrict__ psum, const float* __restrict__ psum2,
                            const float* __restrict__ gamma, const float* __restrict__ beta,
                            float* __restrict__ scale, float* __restrict__ shift) {
  int c = blockIdx.x * 256 + threadIdx.x;
  float s = 0.f, s2 = 0.f;
  for (int i = 0; i < 32; ++i) { s += psum[i * D_ + c]; s2 += psum2[i * D_ + c]; }
  float mean = s * (1.0f / (float)MROWS);
  float var = s2 * (1.0f / (float)MROWS) - mean * mean;
  float rstd = rsqrtf(var + 1e-5f);
  float sc = gamma[c] * rstd;
  scale[c] = sc;
  shift[c] = beta[c] - mean * sc;
}

__global__ void bn_apply(float* __restrict__ x, const float* __restrict__ scale,
                         const float* __restrict__ shift) {
  int i = blockIdx.x * 256 + threadIdx.x;
  int st = gridDim.x * 256;
  const int n4 = MROWS * D_ / 4;
  for (int j = i; j < n4; j += st) {
    float4 v = reinterpret_cast<const float4*>(x)[j];
    int c = (j * 4) & (D_ - 1);
    float4 sc = *reinterpret_cast<const float4*>(&scale[c]);
    float4 sh = *reinterpret_cast<const float4*>(&shift[c]);
    v.x = v.x * sc.x + sh.x; v.y = v.y * sc.y + sh.y;
    v.z = v.z * sc.z + sh.z; v.w = v.w * sc.w + sh.w;
    reinterpret_cast<float4*>(x)[j] = v;
  }
}

extern "C" void kernel_launch(void* const* d_in, const int* in_sizes, int n_in,
                              void* d_out, int out_size, void* d_ws, size_t ws_size,
                              hipStream_t stream) {
  const float* query = (const float*)d_in[0];
  const float* keys  = (const float*)d_in[1];
  const float* Wq    = (const float*)d_in[2];
  const float* Wk    = (const float*)d_in[3];
  const float* Wv    = (const float*)d_in[4];
  const float* gamma = (const float*)d_in[5];
  const float* beta  = (const float*)d_in[6];
  float* out = (float*)d_out;

  // d_out (32MB) doubles as bf16 scratch for the two big input casts:
  // it is fully overwritten by attn_fwd afterwards.
  u16* qb = (u16*)d_out;
  u16* kb = qb + (size_t)MROWS * D_;

  u16* ws  = (u16*)d_ws;
  u16* wqb = ws;
  u16* wkb = wqb + D_ * D_;
  u16* wvb = wkb + D_ * D_;
  u16* Qb  = wvb + D_ * D_;
  u16* Kb  = Qb + (size_t)MROWS * D_;
  u16* Vt  = Kb + (size_t)MROWS * D_;
  float* fbase = (float*)(Vt + (size_t)MROWS * D_);
  float* psum  = fbase;
  float* psum2 = psum + 32 * D_;
  float* scale = psum2 + 32 * D_;
  float* shift = scale + D_;

  cast_bf16<<<dim3(2048), dim3(256), 0, stream>>>(query, qb, MROWS * D_ / 4);
  cast_bf16<<<dim3(2048), dim3(256), 0, stream>>>(keys,  kb, MROWS * D_ / 4);
  cast_bf16<<<dim3(512),  dim3(256), 0, stream>>>(Wq, wqb, D_ * D_ / 4);
  cast_bf16<<<dim3(512),  dim3(256), 0, stream>>>(Wk, wkb, D_ * D_ / 4);
  cast_bf16<<<dim3(512),  dim3(256), 0, stream>>>(Wv, wvb, D_ * D_ / 4);

  gemm_qkv<<<dim3(D_ / BN, MROWS / BM, 3), dim3(256), 0, stream>>>(
      qb, kb, wqb, wkb, wvb, Qb, Kb, Vt);

  attn_fwd<<<dim3(S_ / 64, H_ * B_), dim3(256), 0, stream>>>(Qb, Kb, Vt, query, out);

  bn_partial<<<dim3(D_ / 256, 32), dim3(256), 0, stream>>>(out, psum, psum2);
  bn_finalize<<<dim3(D_ / 256), dim3(256), 0, stream>>>(psum, psum2, gamma, beta, scale, shift);
  bn_apply<<<dim3(2048), dim3(256), 0, stream>>>(out, scale, shift);
}

// Round 2
// 344.904 us; speedup vs baseline: 2.0291x; 2.0291x over previous
//
#include <hip/hip_runtime.h>

typedef unsigned short u16;
typedef __attribute__((ext_vector_type(4))) float f32x4;
typedef __attribute__((ext_vector_type(8))) short bf16x8;
typedef __attribute__((ext_vector_type(4))) unsigned short us4;

#define B_ 4
#define S_ 2048
#define D_ 1024
#define H_ 8
#define DH_ 128
#define MROWS (B_ * S_)   // 8192
#define LOG2E 1.4426950408889634f

__device__ __forceinline__ u16 f2bf(float f) {
  unsigned u = __float_as_uint(f);
  u += 0x7fffu + ((u >> 16) & 1u);   // round-to-nearest-even
  return (u16)(u >> 16);
}

__device__ __forceinline__ void gload_lds16(const void* g, void* l) {
  __builtin_amdgcn_global_load_lds(
      (const __attribute__((address_space(1))) void*)g,
      (__attribute__((address_space(3))) void*)l, 16, 0, 0);
}

// ---------------- cast f32 -> bf16, vectorized x4 ----------------
__global__ void cast_bf16(const float* __restrict__ src, u16* __restrict__ dst, int n4) {
  int i = blockIdx.x * blockDim.x + threadIdx.x;
  int st = gridDim.x * blockDim.x;
  for (; i < n4; i += st) {
    float4 v = reinterpret_cast<const float4*>(src)[i];
    us4 o = { f2bf(v.x), f2bf(v.y), f2bf(v.z), f2bf(v.w) };
    reinterpret_cast<us4*>(dst)[i] = o;
  }
}

// ---------------- fused QKV projection GEMM ----------------
// z=0: Qo = qb@Wq^T, row-major, PRE-SCALED by 1/32 (= 1/sqrt(D), exact pow2)
// z=1: Ko row-major; z=2: Vt transposed per-batch: Vt[(b*1024+col)*2048 + s]
#define BM 128
#define BN 128
#define BKK 32

__global__ __launch_bounds__(256) void gemm_qkv(
    const u16* __restrict__ qb, const u16* __restrict__ kb,
    const u16* __restrict__ wq, const u16* __restrict__ wk, const u16* __restrict__ wv,
    u16* __restrict__ Qo, u16* __restrict__ Ko, u16* __restrict__ Vt)
{
  const int z = blockIdx.z;
  const u16* A = (z == 0) ? qb : kb;
  const u16* W = (z == 0) ? wq : (z == 1) ? wk : wv;
  constexpr int K = D_;

  __shared__ __align__(16) u16 sA[2][BM * BKK];
  __shared__ __align__(16) u16 sB[2][BN * BKK];

  const int tid = threadIdx.x;
  const int w = tid >> 6, lane = tid & 63;
  const int brow = blockIdx.y * BM, bcol = blockIdx.x * BN;

  const int srow = w * 32 + (lane >> 2);
  const int scol = (lane & 3) * 8;
  const u16* gA = A + (brow + srow) * K + scol;
  const u16* gW = W + (bcol + srow) * K + scol;

  const int wr = (w >> 1) * 64, wc = (w & 1) * 64;
  const int fr = lane & 15, fg = lane >> 4;

  f32x4 acc[4][4] = {};

#define STAGE(bufi, k0) do { \
    gload_lds16(gA + (k0),          &sA[bufi][(w * 32) * BKK]);      \
    gload_lds16(gA + 16 * K + (k0), &sA[bufi][(w * 32 + 16) * BKK]); \
    gload_lds16(gW + (k0),          &sB[bufi][(w * 32) * BKK]);      \
    gload_lds16(gW + 16 * K + (k0), &sB[bufi][(w * 32 + 16) * BKK]); \
  } while (0)

  STAGE(0, 0);
  int cur = 0;
  for (int t = 0; t < K / BKK; ++t) {
    __syncthreads();
    if (t + 1 < K / BKK) STAGE(cur ^ 1, (t + 1) * BKK);
    bf16x8 af[4], bfr[4];
#pragma unroll
    for (int m = 0; m < 4; ++m)
      af[m] = *reinterpret_cast<const bf16x8*>(&sA[cur][(wr + m * 16 + fr) * BKK + fg * 8]);
#pragma unroll
    for (int n = 0; n < 4; ++n)
      bfr[n] = *reinterpret_cast<const bf16x8*>(&sB[cur][(wc + n * 16 + fr) * BKK + fg * 8]);
#pragma unroll
    for (int m = 0; m < 4; ++m)
#pragma unroll
      for (int n = 0; n < 4; ++n)
        acc[m][n] = __builtin_amdgcn_mfma_f32_16x16x32_bf16(af[m], bfr[n], acc[m][n], 0, 0, 0);
    cur ^= 1;
  }
#undef STAGE

  if (z < 2) {
    u16* Cp = (z == 0) ? Qo : Ko;
    const float osc = (z == 0) ? 0.03125f : 1.0f;   // fold 1/sqrt(D) into Q
#pragma unroll
    for (int m = 0; m < 4; ++m)
#pragma unroll
      for (int n = 0; n < 4; ++n) {
        int row = brow + wr + m * 16 + fg * 4;
        int col = bcol + wc + n * 16 + fr;
#pragma unroll
        for (int r = 0; r < 4; ++r)
          Cp[(row + r) * D_ + col] = f2bf(acc[m][n][r] * osc);
      }
  } else {
#pragma unroll
    for (int m = 0; m < 4; ++m) {
      int grow0 = brow + wr + m * 16 + fg * 4;
      int b = grow0 >> 11, s0 = grow0 & (S_ - 1);
#pragma unroll
      for (int n = 0; n < 4; ++n) {
        int col = bcol + wc + n * 16 + fr;
        us4 v = { f2bf(acc[m][n][0]), f2bf(acc[m][n][1]),
                  f2bf(acc[m][n][2]), f2bf(acc[m][n][3]) };
        *reinterpret_cast<us4*>(&Vt[((b << 10) + col) * S_ + s0]) = v;
      }
    }
  }
}

// ---------------- flash attention + residual (LDS-staged, swapped QK^T) ---
// 4 waves x 32 q-rows (block = 128 q), KVBLK=64, K/V double-buffered in LDS
// via global_load_lds with XOR-swizzle (inverse-swizzled global source,
// swizzled reads -> 2-way conflicts, free). Swapped QK^T (mfma(K,Q) -> S^T):
// softmax reduce = 15 intra-lane fmax + 2 shuffles. P -> A-frag via small
// swizzled per-wave LDS bounce (packed 8B writes). Defer-max (THR=8).
__global__ __launch_bounds__(256, 2) void attn_fwd(
    const u16* __restrict__ Qb, const u16* __restrict__ Kb, const u16* __restrict__ Vt,
    const float* __restrict__ query, float* __restrict__ out)
{
  // K tile: logical [64 r][16 c(16B)], phys byte = r*256 + (c^(r&7))*16
  // V tile: logical [128 dh][8 c(16B)], phys byte = dh*128 + (c^(dh&7))*16
  // P bounce per wave,m: logical [16 q][64 k], phys u16 = q*64 + ((k>>3)^(q&7))*8 + (k&7)
  __shared__ __align__(16) u16 sK[2][64 * 128];
  __shared__ __align__(16) u16 sV[2][128 * 64];
  __shared__ __align__(16) u16 plds[4][2][16 * 64];

  const int tid = threadIdx.x;
  const int w = tid >> 6, lane = tid & 63;
  const int g = lane >> 4, ql = lane & 15;
  const int hb = blockIdx.y;
  const int b = hb & (B_ - 1), h = hb >> 2;
  const int q0 = blockIdx.x * 128 + w * 32;

  // Q fragments (Qb pre-scaled by 1/32): B-operand, lane holds Q row q, dh fg*8
  bf16x8 qf[2][4];
#pragma unroll
  for (int m = 0; m < 2; ++m)
#pragma unroll
    for (int kk = 0; kk < 4; ++kk)
      qf[m][kk] = *reinterpret_cast<const bf16x8*>(
          Qb + (size_t)(b * S_ + q0 + m * 16 + ql) * D_ + h * DH_ + kk * 32 + g * 8);

  // staging source addrs (inverse-swizzled): wave w stages instrs a = w*4+j
  const u16* gK[4];
  const u16* gV[4];
#pragma unroll
  for (int j = 0; j < 4; ++j) {
    int a = w * 4 + j;
    int rK = a * 4 + g;                       // tile row
    int cK = (lane & 15) ^ (rK & 7);          // logical 16B chunk
    gK[j] = Kb + (size_t)(b * S_ + rK) * D_ + h * DH_ + cK * 8;
    int dhV = a * 8 + (lane >> 3);
    int cV = (lane & 7) ^ (lane >> 3);
    gV[j] = Vt + (size_t)((b << 10) + h * DH_ + dhV) * S_ + cV * 8;
  }

#define ASTAGE(bufi, kv) do { \
    _Pragma("unroll") \
    for (int j = 0; j < 4; ++j) { \
      gload_lds16(gK[j] + (size_t)(kv) * D_, &sK[bufi][(w * 4 + j) * 512]); \
      gload_lds16(gV[j] + (kv),              &sV[bufi][(w * 4 + j) * 512]); \
    } \
  } while (0)

  const float NEG_INF = -__builtin_inff();
  float m_r[2] = { NEG_INF, NEG_INF };
  float l_r[2] = { 0.f, 0.f };
  f32x4 acc[2][8] = {};
  const int sbase = ((lane >> 4) << 2);       // shfl src base for q = g*4+r

  ASTAGE(0, 0);
  int cur = 0;
  for (int kv = 0; kv < S_; kv += 64) {
    __syncthreads();                           // drains vmcnt: buf[cur] ready
    if (kv + 64 < S_) ASTAGE(cur ^ 1, kv + 64);

    // QK^T swapped: sc[m][t][r] = S^T[k = t*16+g*4+r][q = m*16+ql]
    f32x4 sc[2][4] = {};
#pragma unroll
    for (int t = 0; t < 4; ++t) {
      int r = t * 16 + ql;
#pragma unroll
      for (int kk = 0; kk < 4; ++kk) {
        bf16x8 kf = *reinterpret_cast<const bf16x8*>(
            &sK[cur][r * 128 + (((kk * 4 + g) ^ (ql & 7)) << 3)]);
        sc[0][t] = __builtin_amdgcn_mfma_f32_16x16x32_bf16(kf, qf[0][kk], sc[0][t], 0, 0, 0);
        sc[1][t] = __builtin_amdgcn_mfma_f32_16x16x32_bf16(kf, qf[1][kk], sc[1][t], 0, 0, 0);
      }
    }

    // online softmax per m-tile
#pragma unroll
    for (int m = 0; m < 2; ++m) {
      float mx = sc[m][0][0];
#pragma unroll
      for (int t = 0; t < 4; ++t)
#pragma unroll
        for (int r = 0; r < 4; ++r)
          mx = fmaxf(mx, sc[m][t][r]);
      mx = fmaxf(mx, __shfl_xor(mx, 16, 64));
      mx = fmaxf(mx, __shfl_xor(mx, 32, 64));
      if (!__all(mx <= m_r[m] + 8.0f)) {       // defer-max: rare
        float mn = fmaxf(m_r[m], mx);
        float al = exp2f((m_r[m] - mn) * LOG2E);
        m_r[m] = mn;
        l_r[m] *= al;
        float alb[4];
#pragma unroll
        for (int r = 0; r < 4; ++r) alb[r] = __shfl(al, sbase + r, 64);
#pragma unroll
        for (int n = 0; n < 8; ++n)
#pragma unroll
          for (int r = 0; r < 4; ++r) acc[m][n][r] *= alb[r];
      }
      float ssum = 0.f;
      u16* pw = &plds[w][m][0];
#pragma unroll
      for (int t = 0; t < 4; ++t) {
        float p0 = exp2f((sc[m][t][0] - m_r[m]) * LOG2E);
        float p1 = exp2f((sc[m][t][1] - m_r[m]) * LOG2E);
        float p2 = exp2f((sc[m][t][2] - m_r[m]) * LOG2E);
        float p3 = exp2f((sc[m][t][3] - m_r[m]) * LOG2E);
        ssum += (p0 + p1) + (p2 + p3);
        us4 pk = { f2bf(p0), f2bf(p1), f2bf(p2), f2bf(p3) };
        // k base = t*16+g*4 -> chunk c = t*2+(g>>1), in-chunk (g&1)*4
        *reinterpret_cast<us4*>(
            &pw[ql * 64 + (((t * 2 + (g >> 1)) ^ (ql & 7)) << 3) + ((g & 1) << 2)]) = pk;
      }
      ssum += __shfl_xor(ssum, 16, 64);
      ssum += __shfl_xor(ssum, 32, 64);
      l_r[m] += ssum;
    }
    asm volatile("s_waitcnt lgkmcnt(0)" ::: "memory");   // P writes visible (wave-local)

    bf16x8 pa[2][2];
#pragma unroll
    for (int m = 0; m < 2; ++m)
#pragma unroll
      for (int kt = 0; kt < 2; ++kt)
        pa[m][kt] = *reinterpret_cast<const bf16x8*>(
            &plds[w][m][ql * 64 + (((kt * 4 + g) ^ (ql & 7)) << 3)]);

    // PV: acc[m][n] += P[m] @ V   (vf shared across m)
#pragma unroll
    for (int kt = 0; kt < 2; ++kt)
#pragma unroll
      for (int n = 0; n < 8; ++n) {
        int dh = n * 16 + ql;
        bf16x8 vf = *reinterpret_cast<const bf16x8*>(
            &sV[cur][dh * 64 + (((kt * 4 + g) ^ (ql & 7)) << 3)]);
        acc[0][n] = __builtin_amdgcn_mfma_f32_16x16x32_bf16(pa[0][kt], vf, acc[0][n], 0, 0, 0);
        acc[1][n] = __builtin_amdgcn_mfma_f32_16x16x32_bf16(pa[1][kt], vf, acc[1][n], 0, 0, 0);
      }
    cur ^= 1;
  }
#undef ASTAGE

  // epilogue: O /= l, + residual. Stats live on lanes by q=ql; acc rows are q=g*4+r.
#pragma unroll
  for (int m = 0; m < 2; ++m) {
    float inv = 1.0f / l_r[m];
    float invb[4];
#pragma unroll
    for (int r = 0; r < 4; ++r) invb[r] = __shfl(inv, sbase + r, 64);
#pragma unroll
    for (int n = 0; n < 8; ++n)
#pragma unroll
      for (int r = 0; r < 4; ++r) {
        int row = b * S_ + q0 + m * 16 + ((lane >> 4) << 2) + r;
        int col = h * DH_ + n * 16 + ql;
        int idx = row * D_ + col;
        out[idx] = acc[m][n][r] * invb[r] + query[idx];
      }
  }
}

// ---------------- batch-norm (training-style, batch stats) ----------------
__global__ void bn_partial(const float* __restrict__ x, float* __restrict__ psum,
                           float* __restrict__ psum2) {
  int c = blockIdx.x * 256 + threadIdx.x;
  int r0 = blockIdx.y * 256;
  float s = 0.f, s2 = 0.f;
  for (int r = r0; r < r0 + 256; ++r) {
    float v = x[r * D_ + c];
    s += v; s2 += v * v;
  }
  psum[blockIdx.y * D_ + c] = s;
  psum2[blockIdx.y * D_ + c] = s2;
}

__global__ void bn_finalize(const float* __restrict__ psum, const float* __restrict__ psum2,
                            const float* __restrict__ gamma, const float* __restrict__ beta,
                            float* __restrict__ scale, float* __restrict__ shift) {
  int c = blockIdx.x * 256 + threadIdx.x;
  float s = 0.f, s2 = 0.f;
  for (int i = 0; i < 32; ++i) { s += psum[i * D_ + c]; s2 += psum2[i * D_ + c]; }
  float mean = s * (1.0f / (float)MROWS);
  float var = s2 * (1.0f / (float)MROWS) - mean * mean;
  float rstd = rsqrtf(var + 1e-5f);
  float sc = gamma[c] * rstd;
  scale[c] = sc;
  shift[c] = beta[c] - mean * sc;
}

__global__ void bn_apply(float* __restrict__ x, const float* __restrict__ scale,
                         const float* __restrict__ shift) {
  int i = blockIdx.x * 256 + threadIdx.x;
  int st = gridDim.x * 256;
  const int n4 = MROWS * D_ / 4;
  for (int j = i; j < n4; j += st) {
    float4 v = reinterpret_cast<const float4*>(x)[j];
    int c = (j * 4) & (D_ - 1);
    float4 sc = *reinterpret_cast<const float4*>(&scale[c]);
    float4 sh = *reinterpret_cast<const float4*>(&shift[c]);
    v.x = v.x * sc.x + sh.x; v.y = v.y * sc.y + sh.y;
    v.z = v.z * sc.z + sh.z; v.w = v.w * sc.w + sh.w;
    reinterpret_cast<float4*>(x)[j] = v;
  }
}

extern "C" void kernel_launch(void* const* d_in, const int* in_sizes, int n_in,
                              void* d_out, int out_size, void* d_ws, size_t ws_size,
                              hipStream_t stream) {
  const float* query = (const float*)d_in[0];
  const float* keys  = (const float*)d_in[1];
  const float* Wq    = (const float*)d_in[2];
  const float* Wk    = (const float*)d_in[3];
  const float* Wv    = (const float*)d_in[4];
  const float* gamma = (const float*)d_in[5];
  const float* beta  = (const float*)d_in[6];
  float* out = (float*)d_out;

  // d_out (32MB) doubles as bf16 scratch for the two big input casts.
  u16* qb = (u16*)d_out;
  u16* kb = qb + (size_t)MROWS * D_;

  u16* ws  = (u16*)d_ws;
  u16* wqb = ws;
  u16* wkb = wqb + D_ * D_;
  u16* wvb = wkb + D_ * D_;
  u16* Qb  = wvb + D_ * D_;
  u16* Kb  = Qb + (size_t)MROWS * D_;
  u16* Vt  = Kb + (size_t)MROWS * D_;
  float* fbase = (float*)(Vt + (size_t)MROWS * D_);
  float* psum  = fbase;
  float* psum2 = psum + 32 * D_;
  float* scale = psum2 + 32 * D_;
  float* shift = scale + D_;

  cast_bf16<<<dim3(2048), dim3(256), 0, stream>>>(query, qb, MROWS * D_ / 4);
  cast_bf16<<<dim3(2048), dim3(256), 0, stream>>>(keys,  kb, MROWS * D_ / 4);
  cast_bf16<<<dim3(512),  dim3(256), 0, stream>>>(Wq, wqb, D_ * D_ / 4);
  cast_bf16<<<dim3(512),  dim3(256), 0, stream>>>(Wk, wkb, D_ * D_ / 4);
  cast_bf16<<<dim3(512),  dim3(256), 0, stream>>>(Wv, wvb, D_ * D_ / 4);

  gemm_qkv<<<dim3(D_ / BN, MROWS / BM, 3), dim3(256), 0, stream>>>(
      qb, kb, wqb, wkb, wvb, Qb, Kb, Vt);

  attn_fwd<<<dim3(S_ / 128, H_ * B_), dim3(256), 0, stream>>>(Qb, Kb, Vt, query, out);

  bn_partial<<<dim3(D_ / 256, 32), dim3(256), 0, stream>>>(out, psum, psum2);
  bn_finalize<<<dim3(D_ / 256), dim3(256), 0, stream>>>(psum, psum2, gamma, beta, scale, shift);
  bn_apply<<<dim3(2048), dim3(256), 0, stream>>>(out, scale, shift);
}